// Round 13
// baseline (59.084 us; speedup 1.0000x reference)
//
#include <hip/hip_runtime.h>
#include <math.h>

// Problem constants
#define BATCH 4096
#define NFEAT 2048
#define NNEUR 1024
#define NTGT  8
#define NNZ1  65536
#define NNZ2  8192

// GEMM: h[m][n] = sigmoid( sum_k W1b[m][k]*xbf(n,k) + b1[m] ), fused layer-2
// epilogue (atomicAdd into b2-prefilled out). M=1024, N=4096, K=2048.
// R12 loop structure (reg-staged, 2-deep, compiler-counted waits) +
// K-SPLIT-IN-BLOCK for residency: tile 64x64, BK=64, 4 waves =
// {2 n-halves x 2 K-halves}; wave = 64m x 32n x 32k per step.
// Grid 1024 = 4 blocks/CU = 16 waves/CU = 4 waves/SIMD (2x R12).
// K-halves combined via LDS after the loop; kh=0 waves run the epilogue.
#define BM 64
#define BN 64
#define BK 64
#define KSTEPS (NFEAT / BK)   // 32

typedef short  bf16x8 __attribute__((ext_vector_type(8)));
typedef float  f32x4  __attribute__((ext_vector_type(4)));

// ---------------- workspace layout (bytes) ----------------
#define OFF_W1F  ((size_t)0)
#define OFF_W2D  ((size_t)8388608)
#define OFF_W1B  ((size_t)8421376)

#define ZERO_FLOAT4 526336               // W1f+W2d contiguous
#define OUT_FLOAT4  (BATCH * NTGT / 4)   // 8192

__device__ __forceinline__ unsigned short f2bf(float f) {
    union { float f; unsigned int u; } a; a.f = f;
    unsigned int u = a.u;
    u += 0x7fffu + ((u >> 16) & 1u);   // round-to-nearest-even
    return (unsigned short)(u >> 16);
}

// 8x f32 -> 8x bf16 (RNE) packed in uint4, via v_cvt_pk_bf16_f32
__device__ __forceinline__ uint4 pk8(float4 lo, float4 hi) {
    uint4 r;
    asm("v_cvt_pk_bf16_f32 %0, %1, %2" : "=v"(r.x) : "v"(lo.x), "v"(lo.y));
    asm("v_cvt_pk_bf16_f32 %0, %1, %2" : "=v"(r.y) : "v"(lo.z), "v"(lo.w));
    asm("v_cvt_pk_bf16_f32 %0, %1, %2" : "=v"(r.z) : "v"(hi.x), "v"(hi.y));
    asm("v_cvt_pk_bf16_f32 %0, %1, %2" : "=v"(r.w) : "v"(hi.z), "v"(hi.w));
    return r;
}

// zero W1f+W2d and pre-fill out with b2 (k_gemm atomicAdds into out)
__global__ void k_zero(float4* __restrict__ ws4, float4* __restrict__ out4,
                       const float* __restrict__ b2) {
    int i = blockIdx.x * blockDim.x + threadIdx.x;
    if (i < ZERO_FLOAT4) {
        ws4[i] = make_float4(0.f, 0.f, 0.f, 0.f);
    } else {
        int j = i - ZERO_FLOAT4;
        if (j < OUT_FLOAT4) {
            int p = (j & 1) * 4;
            out4[j] = make_float4(b2[p], b2[p + 1], b2[p + 2], b2[p + 3]);
        }
    }
}

// scatter-add edges into dense W1f and W2d (handles duplicate edges by summing)
__global__ void k_build(const float* __restrict__ w1, const int* __restrict__ c1o,
                        const int* __restrict__ c1i,
                        const float* __restrict__ w2, const int* __restrict__ c2o,
                        const int* __restrict__ c2i,
                        float* __restrict__ W1f, float* __restrict__ W2d) {
    int i = blockIdx.x * blockDim.x + threadIdx.x;
    if (i < NNZ1) {
        atomicAdd(&W1f[(size_t)c1o[i] * NFEAT + c1i[i]], w1[i]);
    } else {
        int j = i - NNZ1;
        if (j < NNZ2) atomicAdd(&W2d[c2i[j] * NTGT + c2o[j]], w2[j]);
    }
}

// convert W1f -> W1b only (x is consumed as f32 by k_gemm)
__global__ void k_convert(const float* __restrict__ W1f, unsigned short* __restrict__ W1b) {
    int i = blockIdx.x * blockDim.x + threadIdx.x;   // < NNEUR*NFEAT/4
    float4 v = ((const float4*)W1f)[i];
    ushort4 o;
    o.x = f2bf(v.x); o.y = f2bf(v.y); o.z = f2bf(v.z); o.w = f2bf(v.w);
    ((ushort4*)W1b)[i] = o;
}

// bf16 MFMA GEMM, reg-staged 2-deep compiler-scheduled pipeline, K-split waves,
// fused bias+sigmoid+layer2 epilogue (atomic into out).
__global__ __launch_bounds__(256, 4) void k_gemm(const unsigned short* __restrict__ W1b,
                                                 const float* __restrict__ x,
                                                 const float* __restrict__ b1,
                                                 const float* __restrict__ W2d,
                                                 float* __restrict__ out) {
    __shared__ unsigned short ldsA[2][BM * BK];   // 2 x 8 KB (combine scratch after loop)
    __shared__ unsigned short ldsB[2][BN * BK];   // 2 x 8 KB
    __shared__ float s_w2[BM][NTGT];              // 2 KB
    __shared__ float s_b1[BM];                    // 256 B
    __shared__ float s_pt[BN][NTGT];              // 2 KB

    // bijective XCD swizzle: each XCD gets 8 contiguous n-tiles x 16 m-tiles,
    // m fastest (W1 4MB stays L2-resident per XCD)
    int bid = blockIdx.x;                  // 0..1023
    int v   = bid >> 3;                    // 0..127
    int n0  = ((bid & 7) * 8 + (v >> 4)) * BN;   // 64 n-tiles
    int mt  = v & 15;                      // 16 m-tiles
    int m0  = mt * BM;

    int tid  = threadIdx.x;
    int wv   = tid >> 6;                   // 4 waves
    int lane = tid & 63;
    int wn = wv >> 1, kh = wv & 1;         // n-half, K-half
    int lr = lane & 15, lg = lane >> 4;

    // preload W2d + b1 slices for the epilogue (compiler orders via dataflow)
    for (int i = tid; i < BM * NTGT; i += 256)
        s_w2[i >> 3][i & 7] = W2d[(m0 + (i >> 3)) * NTGT + (i & 7)];
    if (tid < BM) s_b1[tid] = b1[m0 + tid];

    f32x4 zero4 = {0.f, 0.f, 0.f, 0.f};
    f32x4 acc[4][2];
#pragma unroll
    for (int i = 0; i < 4; ++i)
#pragma unroll
        for (int j = 0; j < 2; ++j) acc[i][j] = zero4;

    // ---- reg-staging geometry ----
    // A tile 64x64 bf16 = 512 16B-units: thread t handles u = t, t+256.
    //   unit u: row = u>>3, slot s = u&7; LDS unit = row*8 + (s ^ (row&7)).
    // B tile 64x64 (f32 -> bf16): same unit mapping, two float4 loads per unit.
    int r0 = tid >> 3, s0 = tid & 7;
    const unsigned short* gA0 = &W1b[(size_t)(m0 + r0) * NFEAT + s0 * 8];
    const unsigned short* gA1 = gA0 + 32 * NFEAT;
    const float* gB0 = &x[(size_t)(n0 + r0) * NFEAT + s0 * 8];
    const float* gB1 = gB0 + 32 * NFEAT;
    const int iw0 = r0 * 8 + (s0 ^ (r0 & 7));   // (r0+32)&7 == r0&7 -> +256
    const int iw1 = iw0 + 256;

    // two named register sets (rule #20: no runtime-indexed arrays)
    bf16x8 A0a, A0b;  float4 B0a, B0b, B0c, B0d;
    bf16x8 A1a, A1b;  float4 B1a, B1b, B1c, B1d;
    bf16x8 af[4], bg[2];

#define LOADS0(T) do { int kk = (T) * BK;                           \
        A0a = *(const bf16x8*)(gA0 + kk); A0b = *(const bf16x8*)(gA1 + kk); \
        B0a = *(const float4*)(gB0 + kk); B0b = *(const float4*)(gB0 + kk + 4); \
        B0c = *(const float4*)(gB1 + kk); B0d = *(const float4*)(gB1 + kk + 4); } while (0)
#define LOADS1(T) do { int kk = (T) * BK;                           \
        A1a = *(const bf16x8*)(gA0 + kk); A1b = *(const bf16x8*)(gA1 + kk); \
        B1a = *(const float4*)(gB0 + kk); B1b = *(const float4*)(gB0 + kk + 4); \
        B1c = *(const float4*)(gB1 + kk); B1d = *(const float4*)(gB1 + kk + 4); } while (0)

#define STORE0(BUF) do {                                            \
        bf16x8* dA = (bf16x8*)&ldsA[BUF][0];                        \
        dA[iw0] = A0a; dA[iw1] = A0b;                               \
        uint4* dB = (uint4*)&ldsB[BUF][0];                          \
        dB[iw0] = pk8(B0a, B0b); dB[iw1] = pk8(B0c, B0d); } while (0)
#define STORE1(BUF) do {                                            \
        bf16x8* dA = (bf16x8*)&ldsA[BUF][0];                        \
        dA[iw0] = A1a; dA[iw1] = A1b;                               \
        uint4* dB = (uint4*)&ldsB[BUF][0];                          \
        dB[iw0] = pk8(B1a, B1b); dB[iw1] = pk8(B1c, B1d); } while (0)

    // wave (wn,kh) reads k-chunk slot = kh*4+lg of its rows
#define READF(BUF) do {                                             \
        const unsigned short* bA = ldsA[BUF];                       \
        const unsigned short* bB = ldsB[BUF];                       \
        _Pragma("unroll")                                           \
        for (int i = 0; i < 4; ++i) {                               \
            int rowa = i * 16 + lr;                                 \
            af[i] = *(const bf16x8*)&bA[(rowa * 8 + ((kh * 4 + lg) ^ (rowa & 7))) * 8]; \
        }                                                           \
        _Pragma("unroll")                                           \
        for (int j = 0; j < 2; ++j) {                               \
            int rowb = wn * 32 + j * 16 + lr;                       \
            bg[j] = *(const bf16x8*)&bB[(rowb * 8 + ((kh * 4 + lg) ^ (rowb & 7))) * 8]; \
        }                                                           \
    } while (0)

#define MFMAS() do {                                                \
        _Pragma("unroll")                                           \
        for (int i = 0; i < 4; ++i)                                 \
            _Pragma("unroll")                                       \
            for (int j = 0; j < 2; ++j)                             \
                acc[i][j] = __builtin_amdgcn_mfma_f32_16x16x32_bf16(af[i], bg[j], acc[i][j], 0, 0, 0); \
    } while (0)

#define LDSFENCE() asm volatile("s_waitcnt lgkmcnt(0)" ::: "memory")

    // prologue: tiles 0,1 -> regs; store tile 0 (set1 loads stay in flight)
    LOADS0(0);
    LOADS1(1);
    STORE0(0);            // compiler waits set0's vmcnt precisely
    LDSFENCE();
    __builtin_amdgcn_s_barrier();

    // steady state: 15 pairs cover tiles 0..29.
#pragma unroll 1
    for (int p = 0; p < 15; ++p) {
        int e = 2 * p;
        LOADS0(e + 2);
        STORE1(1);        // waits set1 only (set0 stays in flight)
        READF(0);
        MFMAS();
        LDSFENCE();
        __builtin_amdgcn_s_barrier();
        LOADS1(e + 3);
        STORE0(0);
        READF(1);
        MFMAS();
        LDSFENCE();
        __builtin_amdgcn_s_barrier();
    }
    // tail: buf0 = tile 30 ready; set1 = tile 31 in flight
    STORE1(1);
    READF(0);
    MFMAS();
    LDSFENCE();
    __builtin_amdgcn_s_barrier();
    READF(1);
    MFMAS();

#undef LOADS0
#undef LOADS1
#undef STORE0
#undef STORE1
#undef READF
#undef MFMAS

    // ---- K-half combine: kh=1 waves dump acc into LDS; kh=0 add ----
    LDSFENCE();
    __builtin_amdgcn_s_barrier();          // all LDS reads done; bufs free
    float* cmb = (float*)&ldsA[0][0];      // 16 KB = 2 pairs x 8 KB
    if (kh == 1) {
#pragma unroll
        for (int i = 0; i < 4; ++i)
#pragma unroll
            for (int j = 0; j < 2; ++j)
                *(f32x4*)&cmb[wn * 2048 + (i * 2 + j) * 256 + lane * 4] = acc[i][j];
    }
    LDSFENCE();
    __builtin_amdgcn_s_barrier();

    if (kh == 0) {
#pragma unroll
        for (int i = 0; i < 4; ++i)
#pragma unroll
            for (int j = 0; j < 2; ++j) {
                f32x4 o = *(const f32x4*)&cmb[wn * 2048 + (i * 2 + j) * 256 + lane * 4];
                acc[i][j] += o;
            }

        // ---- fused epilogue: h = sigmoid(acc+b1); pt[j][t] = sum_m h*W2d[m][t]
        // C/D layout: col(n) = lane&15, row(m) = (lane>>4)*4 + reg [m89-verified]
        float pt[2][NTGT];
#pragma unroll
        for (int j = 0; j < 2; ++j)
#pragma unroll
            for (int t = 0; t < NTGT; ++t) pt[j][t] = 0.f;

#pragma unroll
        for (int i = 0; i < 4; ++i) {
#pragma unroll
            for (int r = 0; r < 4; ++r) {
                int ml = i * 16 + lg * 4 + r;
                float bn = s_b1[ml];
#pragma unroll
                for (int j = 0; j < 2; ++j) {
                    float h = 1.f / (1.f + __expf(-(acc[i][j][r] + bn)));
#pragma unroll
                    for (int t = 0; t < NTGT; ++t)
                        pt[j][t] += h * s_w2[ml][t];
                }
            }
        }
        // reduce over lg (lanes lr+16*lg share the same n column)
#pragma unroll
        for (int j = 0; j < 2; ++j)
#pragma unroll
            for (int t = 0; t < NTGT; ++t) {
                float val = pt[j][t];
                val += __shfl_xor(val, 16, 64);
                val += __shfl_xor(val, 32, 64);
                pt[j][t] = val;
            }
        if (lg == 0) {
#pragma unroll
            for (int j = 0; j < 2; ++j) {
                int nl = wn * 32 + j * 16 + lr;
#pragma unroll
                for (int t = 0; t < NTGT; ++t)
                    s_pt[nl][t] = pt[j][t];
            }
        }
    }
    __syncthreads();
    // atomic add 64 n x 8 t into out (pre-filled with b2); coalesced by tid
    for (int idx = tid; idx < BN * NTGT; idx += 256) {
        int nl = idx >> 3, t = idx & 7;
        atomicAdd(&out[(size_t)(n0 + nl) * NTGT + t], s_pt[nl][t]);
    }
}

extern "C" void kernel_launch(void* const* d_in, const int* in_sizes, int n_in,
                              void* d_out, int out_size, void* d_ws, size_t ws_size,
                              hipStream_t stream) {
    (void)in_sizes; (void)n_in; (void)out_size; (void)ws_size;
    const float* x   = (const float*)d_in[0];
    const float* w1  = (const float*)d_in[1];
    const float* b1  = (const float*)d_in[2];
    const float* w2  = (const float*)d_in[3];
    const float* b2  = (const float*)d_in[4];
    const int*   c1o = (const int*)d_in[5];
    const int*   c1i = (const int*)d_in[6];
    const int*   c2o = (const int*)d_in[7];
    const int*   c2i = (const int*)d_in[8];
    float* out = (float*)d_out;

    char* ws = (char*)d_ws;
    float*          W1f  = (float*)(ws + OFF_W1F);
    float*          W2d  = (float*)(ws + OFF_W2D);
    unsigned short* W1b  = (unsigned short*)(ws + OFF_W1B);

    // zero W1f+W2d, pre-fill out with b2
    k_zero<<<(ZERO_FLOAT4 + OUT_FLOAT4 + 255) / 256, 256, 0, stream>>>(
        (float4*)ws, (float4*)out, b2);

    // dense weight build
    k_build<<<(NNZ1 + NNZ2) / 256, 256, 0, stream>>>(w1, c1o, c1i, w2, c2o, c2i, W1f, W2d);

    // fp32 -> bf16 for W1 only (x converted in-register inside k_gemm)
    k_convert<<<NNEUR * NFEAT / 4 / 256, 256, 0, stream>>>(W1f, W1b);

    // layer 1 GEMM + bias + sigmoid + layer-2 (atomic) all fused
    k_gemm<<<(NNEUR / BM) * (BATCH / BN), 256, 0, stream>>>(W1b, x, b1, W2d, out);
}

// Round 14
// 56.792 us; speedup vs baseline: 1.0403x; 1.0403x over previous
//
#include <hip/hip_runtime.h>
#include <math.h>

// Problem constants
#define BATCH 4096
#define NFEAT 2048
#define NNEUR 1024
#define NTGT  8
#define NNZ1  65536
#define NNZ2  8192

// GEMM: h[m][n] = sigmoid( sum_k W1b[m][k]*xbf(n,k) + b1[m] ), fused layer-2
// epilogue (atomicAdd into b2-prefilled out). M=1024, N=4096, K=2048.
// Traffic-minimized design (R13 post-mortem: time == sum of LDS+L2+MFMA bytes):
//   wave tile 64x64 (LDS-read B/FLOP 0.031 vs 0.047), block 128x128, BK=32,
//   4 waves (2m x 2n), mfma_f32_32x32x16_bf16 (2x2 frags/wave, 8 MFMA/step),
//   reg-staged 2-deep compiler-counted pipeline (R12 loop), B f32 in-reg cvt.
// Grid 256 = 1 block/CU.
#define BM 128
#define BN 128
#define BK 32
#define KSTEPS (NFEAT / BK)   // 64

typedef short  bf16x8 __attribute__((ext_vector_type(8)));
typedef float  f32x16 __attribute__((ext_vector_type(16)));

// ---------------- workspace layout (bytes) ----------------
#define OFF_W1F  ((size_t)0)
#define OFF_W2D  ((size_t)8388608)
#define OFF_W1B  ((size_t)8421376)

#define ZERO_FLOAT4 526336               // W1f+W2d contiguous
#define OUT_FLOAT4  (BATCH * NTGT / 4)   // 8192

__device__ __forceinline__ unsigned short f2bf(float f) {
    union { float f; unsigned int u; } a; a.f = f;
    unsigned int u = a.u;
    u += 0x7fffu + ((u >> 16) & 1u);   // round-to-nearest-even
    return (unsigned short)(u >> 16);
}

// 8x f32 -> 8x bf16 (RNE) packed in uint4, via v_cvt_pk_bf16_f32
__device__ __forceinline__ uint4 pk8(float4 lo, float4 hi) {
    uint4 r;
    asm("v_cvt_pk_bf16_f32 %0, %1, %2" : "=v"(r.x) : "v"(lo.x), "v"(lo.y));
    asm("v_cvt_pk_bf16_f32 %0, %1, %2" : "=v"(r.y) : "v"(lo.z), "v"(lo.w));
    asm("v_cvt_pk_bf16_f32 %0, %1, %2" : "=v"(r.z) : "v"(hi.x), "v"(hi.y));
    asm("v_cvt_pk_bf16_f32 %0, %1, %2" : "=v"(r.w) : "v"(hi.z), "v"(hi.w));
    return r;
}

// zero W1f+W2d and pre-fill out with b2 (k_gemm atomicAdds into out)
__global__ void k_zero(float4* __restrict__ ws4, float4* __restrict__ out4,
                       const float* __restrict__ b2) {
    int i = blockIdx.x * blockDim.x + threadIdx.x;
    if (i < ZERO_FLOAT4) {
        ws4[i] = make_float4(0.f, 0.f, 0.f, 0.f);
    } else {
        int j = i - ZERO_FLOAT4;
        if (j < OUT_FLOAT4) {
            int p = (j & 1) * 4;
            out4[j] = make_float4(b2[p], b2[p + 1], b2[p + 2], b2[p + 3]);
        }
    }
}

// scatter-add edges into dense W1f and W2d (handles duplicate edges by summing)
__global__ void k_build(const float* __restrict__ w1, const int* __restrict__ c1o,
                        const int* __restrict__ c1i,
                        const float* __restrict__ w2, const int* __restrict__ c2o,
                        const int* __restrict__ c2i,
                        float* __restrict__ W1f, float* __restrict__ W2d) {
    int i = blockIdx.x * blockDim.x + threadIdx.x;
    if (i < NNZ1) {
        atomicAdd(&W1f[(size_t)c1o[i] * NFEAT + c1i[i]], w1[i]);
    } else {
        int j = i - NNZ1;
        if (j < NNZ2) atomicAdd(&W2d[c2i[j] * NTGT + c2o[j]], w2[j]);
    }
}

// convert W1f -> W1b only (x is consumed as f32 by k_gemm)
__global__ void k_convert(const float* __restrict__ W1f, unsigned short* __restrict__ W1b) {
    int i = blockIdx.x * blockDim.x + threadIdx.x;   // < NNEUR*NFEAT/4
    float4 v = ((const float4*)W1f)[i];
    ushort4 o;
    o.x = f2bf(v.x); o.y = f2bf(v.y); o.z = f2bf(v.z); o.w = f2bf(v.w);
    ((ushort4*)W1b)[i] = o;
}

// bf16 MFMA GEMM, 32x32x16 intrinsic, wave tile 64x64, reg-staged 2-deep
// compiler-scheduled pipeline, fused bias+sigmoid+layer2 epilogue.
__global__ __launch_bounds__(256) void k_gemm(const unsigned short* __restrict__ W1b,
                                              const float* __restrict__ x,
                                              const float* __restrict__ b1,
                                              const float* __restrict__ W2d,
                                              float* __restrict__ out) {
    __shared__ unsigned short ldsA[2][BM * BK];   // 2 x 8 KB
    __shared__ unsigned short ldsB[2][BN * BK];   // 2 x 8 KB
    __shared__ float s_w2[BM][NTGT];              // 4 KB
    __shared__ float s_b1[BM];                    // 512 B
    __shared__ float s_pt[2][BN][NTGT];           // 8 KB

    // bijective XCD swizzle: each XCD gets 4 contiguous n-tiles x 8 m-tiles
    int bid = blockIdx.x;                  // 0..255
    int v   = bid >> 3;                    // 0..31
    int n0  = ((bid & 7) * 4 + (v >> 3)) * BN;   // 32 n-tiles
    int mt  = v & 7;                       // 8 m-tiles
    int m0  = mt * BM;

    int tid  = threadIdx.x;
    int wv   = tid >> 6;                   // 4 waves: 2m x 2n
    int lane = tid & 63;
    int wm = wv >> 1, wn = wv & 1;
    int lc = lane & 31;                    // 32x32 operand row/col
    int lh = lane >> 5;                    // k-half selector

    // preload W2d + b1 slices for the epilogue
    for (int i = tid; i < BM * NTGT; i += 256)
        s_w2[i >> 3][i & 7] = W2d[(m0 + (i >> 3)) * NTGT + (i & 7)];
    if (tid < BM) s_b1[tid] = b1[m0 + tid];

    f32x16 acc[2][2];
#pragma unroll
    for (int i = 0; i < 2; ++i)
#pragma unroll
        for (int j = 0; j < 2; ++j) acc[i][j] = (f32x16)(0.f);

    // ---- staging geometry ----
    // A/B bf16 tile 128x32 = 512 16B-units; unit u: row=u>>2, slot s=u&3.
    // LDS unit = row*4 + (s ^ (row&3) ^ ((row>>2)&3)).
    // Thread t handles units t and t+256 (rows r0 and r0+64; same XOR).
    // B loads f32 (two float4 per unit), cvt at store via pk8.
    int r0 = tid >> 2, s0 = tid & 3;
    const unsigned short* gA0 = &W1b[(size_t)(m0 + r0) * NFEAT + s0 * 8];
    const unsigned short* gA1 = gA0 + (size_t)64 * NFEAT;
    const float* gB0 = &x[(size_t)(n0 + r0) * NFEAT + s0 * 8];
    const float* gB1 = gB0 + (size_t)64 * NFEAT;
    const int iw0 = r0 * 4 + (s0 ^ (r0 & 3) ^ ((r0 >> 2) & 3));
    const int iw1 = iw0 + 256;

    // two named register sets (rule #20)
    bf16x8 A0a, A0b;  float4 B0a, B0b, B0c, B0d;
    bf16x8 A1a, A1b;  float4 B1a, B1b, B1c, B1d;
    bf16x8 af[2][2], bg[2][2];   // [frag][kslot], constant-indexed only

#define LOADS0(T) do { int kk = (T) * BK;                           \
        A0a = *(const bf16x8*)(gA0 + kk); A0b = *(const bf16x8*)(gA1 + kk); \
        B0a = *(const float4*)(gB0 + kk); B0b = *(const float4*)(gB0 + kk + 4); \
        B0c = *(const float4*)(gB1 + kk); B0d = *(const float4*)(gB1 + kk + 4); } while (0)
#define LOADS1(T) do { int kk = (T) * BK;                           \
        A1a = *(const bf16x8*)(gA0 + kk); A1b = *(const bf16x8*)(gA1 + kk); \
        B1a = *(const float4*)(gB0 + kk); B1b = *(const float4*)(gB0 + kk + 4); \
        B1c = *(const float4*)(gB1 + kk); B1d = *(const float4*)(gB1 + kk + 4); } while (0)

#define STORE0(BUF) do {                                            \
        bf16x8* dA = (bf16x8*)&ldsA[BUF][0];                        \
        dA[iw0] = A0a; dA[iw1] = A0b;                               \
        uint4* dB = (uint4*)&ldsB[BUF][0];                          \
        dB[iw0] = pk8(B0a, B0b); dB[iw1] = pk8(B0c, B0d); } while (0)
#define STORE1(BUF) do {                                            \
        bf16x8* dA = (bf16x8*)&ldsA[BUF][0];                        \
        dA[iw0] = A1a; dA[iw1] = A1b;                               \
        uint4* dB = (uint4*)&ldsB[BUF][0];                          \
        dB[iw0] = pk8(B1a, B1b); dB[iw1] = pk8(B1c, B1d); } while (0)

    // fragment reads: 32x32x16 operand layout: lane = row/col (lc) + 32*khalf
    // (lh); frag (f,kk): row = w*64 + f*32 + lc, unit slot = kk*2 + lh.
#define READF(BUF) do {                                             \
        const unsigned short* bA = ldsA[BUF];                       \
        const unsigned short* bB = ldsB[BUF];                       \
        _Pragma("unroll")                                           \
        for (int f = 0; f < 2; ++f) {                               \
            int ra = wm * 64 + f * 32 + lc;                         \
            int xa = (ra & 3) ^ ((ra >> 2) & 3);                    \
            af[f][0] = *(const bf16x8*)&bA[(ra * 4 + ((lh)     ^ xa)) * 8]; \
            af[f][1] = *(const bf16x8*)&bA[(ra * 4 + ((2 + lh) ^ xa)) * 8]; \
            int rb = wn * 64 + f * 32 + lc;                         \
            int xb2 = (rb & 3) ^ ((rb >> 2) & 3);                   \
            bg[f][0] = *(const bf16x8*)&bB[(rb * 4 + ((lh)     ^ xb2)) * 8]; \
            bg[f][1] = *(const bf16x8*)&bB[(rb * 4 + ((2 + lh) ^ xb2)) * 8]; \
        }                                                           \
    } while (0)

#define MFMAS() do {                                                \
        _Pragma("unroll")                                           \
        for (int kk = 0; kk < 2; ++kk)                              \
            _Pragma("unroll")                                       \
            for (int i = 0; i < 2; ++i)                             \
                _Pragma("unroll")                                   \
                for (int j = 0; j < 2; ++j)                         \
                    acc[i][j] = __builtin_amdgcn_mfma_f32_32x32x16_bf16(af[i][kk], bg[j][kk], acc[i][j], 0, 0, 0); \
    } while (0)

#define LDSFENCE() asm volatile("s_waitcnt lgkmcnt(0)" ::: "memory")

    // prologue: tiles 0,1 -> regs; store tile 0 (set1 loads stay in flight)
    LOADS0(0);
    LOADS1(1);
    STORE0(0);            // compiler waits set0's vmcnt precisely
    LDSFENCE();
    __builtin_amdgcn_s_barrier();

    // steady state: 31 pairs cover tiles 0..61.
#pragma unroll 1
    for (int p = 0; p < KSTEPS / 2 - 1; ++p) {
        int e = 2 * p;
        LOADS0(e + 2);
        STORE1(1);        // waits set1 only (set0 stays in flight)
        READF(0);
        MFMAS();
        LDSFENCE();
        __builtin_amdgcn_s_barrier();
        LOADS1(e + 3);
        STORE0(0);
        READF(1);
        MFMAS();
        LDSFENCE();
        __builtin_amdgcn_s_barrier();
    }
    // tail: buf0 = tile 62 ready; set1 = tile 63 in flight
    STORE1(1);
    READF(0);
    MFMAS();
    LDSFENCE();
    __builtin_amdgcn_s_barrier();
    READF(1);
    MFMAS();

#undef LOADS0
#undef LOADS1
#undef STORE0
#undef STORE1
#undef READF
#undef MFMAS

    // ---- fused epilogue: h = sigmoid(acc + b1); pt[j][t] = sum_m h*W2d[m][t]
    // 32x32 C/D layout: col(n) = lane&31, row(m) = (reg&3)+8*(reg>>2)+4*(lane>>5)
    // [m74/m101-verified]
    float pt[2][NTGT];
#pragma unroll
    for (int j = 0; j < 2; ++j)
#pragma unroll
        for (int t = 0; t < NTGT; ++t) pt[j][t] = 0.f;

#pragma unroll
    for (int i = 0; i < 2; ++i) {
#pragma unroll
        for (int r = 0; r < 16; ++r) {
            int ml = wm * 64 + i * 32 + (r & 3) + 8 * (r >> 2) + 4 * lh;
            float bn = s_b1[ml];
#pragma unroll
            for (int j = 0; j < 2; ++j) {
                float h = 1.f / (1.f + __expf(-(acc[i][j][r] + bn)));
#pragma unroll
                for (int t = 0; t < NTGT; ++t)
                    pt[j][t] += h * s_w2[ml][t];
            }
        }
    }
    // reduce over lh (lanes lc and lc+32 share the same n column)
#pragma unroll
    for (int j = 0; j < 2; ++j)
#pragma unroll
        for (int t = 0; t < NTGT; ++t)
            pt[j][t] += __shfl_xor(pt[j][t], 32, 64);
    if (lh == 0) {
#pragma unroll
        for (int j = 0; j < 2; ++j) {
            int nl = wn * 64 + j * 32 + lc;
#pragma unroll
            for (int t = 0; t < NTGT; ++t)
                s_pt[wm][nl][t] = pt[j][t];
        }
    }
    __syncthreads();
    // atomic add 128 n x 8 t into out (pre-filled with b2); coalesced by tid
    for (int idx = tid; idx < BN * NTGT; idx += 256) {
        int nl = idx >> 3, t = idx & 7;
        atomicAdd(&out[(size_t)(n0 + nl) * NTGT + t], s_pt[0][nl][t] + s_pt[1][nl][t]);
    }
}

extern "C" void kernel_launch(void* const* d_in, const int* in_sizes, int n_in,
                              void* d_out, int out_size, void* d_ws, size_t ws_size,
                              hipStream_t stream) {
    (void)in_sizes; (void)n_in; (void)out_size; (void)ws_size;
    const float* x   = (const float*)d_in[0];
    const float* w1  = (const float*)d_in[1];
    const float* b1  = (const float*)d_in[2];
    const float* w2  = (const float*)d_in[3];
    const float* b2  = (const float*)d_in[4];
    const int*   c1o = (const int*)d_in[5];
    const int*   c1i = (const int*)d_in[6];
    const int*   c2o = (const int*)d_in[7];
    const int*   c2i = (const int*)d_in[8];
    float* out = (float*)d_out;

    char* ws = (char*)d_ws;
    float*          W1f  = (float*)(ws + OFF_W1F);
    float*          W2d  = (float*)(ws + OFF_W2D);
    unsigned short* W1b  = (unsigned short*)(ws + OFF_W1B);

    // zero W1f+W2d, pre-fill out with b2
    k_zero<<<(ZERO_FLOAT4 + OUT_FLOAT4 + 255) / 256, 256, 0, stream>>>(
        (float4*)ws, (float4*)out, b2);

    // dense weight build
    k_build<<<(NNZ1 + NNZ2) / 256, 256, 0, stream>>>(w1, c1o, c1i, w2, c2o, c2i, W1f, W2d);

    // fp32 -> bf16 for W1 only (x converted in-register inside k_gemm)
    k_convert<<<NNEUR * NFEAT / 4 / 256, 256, 0, stream>>>(W1f, W1b);

    // layer 1 GEMM + bias + sigmoid + layer-2 (atomic) all fused
    k_gemm<<<(NNEUR / BM) * (BATCH / BN), 256, 0, stream>>>(W1b, x, b1, W2d, out);
}

// Round 15
// 52.594 us; speedup vs baseline: 1.1234x; 1.0798x over previous
//
#include <hip/hip_runtime.h>
#include <math.h>

// Problem constants
#define BATCH 4096
#define NFEAT 2048
#define NNEUR 1024
#define NTGT  8
#define NNZ1  65536
#define NNZ2  8192

// GEMM: h[m][n] = sigmoid( sum_k W1[m][k]*x[n][k] + b1[m] ), fused layer-2
// epilogue (atomicAdd into b2-prefilled out). M=1024, N=4096, K=2048.
// R12 loop (reg-staged B, 2-deep, compiler-counted waits) + A-DIRECT:
// W1 pre-packed in MFMA-fragment order (k_pack) and loaded global->regs
// (8 coalesced 1KB reads/wave/step) -- A's LDS write+read removed entirely.
// XCD map splits M (A 2MB/XCD, L2-resident). 128x64 tile, BK=64, 4 waves
// (2m x 2n, wave 64x32), grid 512 = 2 blocks/CU.
#define BM 128
#define BN 64
#define BK 64
#define KSTEPS (NFEAT / BK)   // 32

typedef short  bf16x8 __attribute__((ext_vector_type(8)));
typedef float  f32x4  __attribute__((ext_vector_type(4)));

// ---------------- workspace layout (bytes) ----------------
#define OFF_W1F  ((size_t)0)
#define OFF_W2D  ((size_t)8388608)
#define OFF_W1P  ((size_t)8421376)       // fragment-packed W1 (4 MB)

#define ZERO_FLOAT4 526336               // W1f+W2d contiguous
#define OUT_FLOAT4  (BATCH * NTGT / 4)   // 8192

// 8x f32 -> 8x bf16 (RNE) packed in uint4, via v_cvt_pk_bf16_f32
__device__ __forceinline__ uint4 pk8(float4 lo, float4 hi) {
    uint4 r;
    asm("v_cvt_pk_bf16_f32 %0, %1, %2" : "=v"(r.x) : "v"(lo.x), "v"(lo.y));
    asm("v_cvt_pk_bf16_f32 %0, %1, %2" : "=v"(r.y) : "v"(lo.z), "v"(lo.w));
    asm("v_cvt_pk_bf16_f32 %0, %1, %2" : "=v"(r.z) : "v"(hi.x), "v"(hi.y));
    asm("v_cvt_pk_bf16_f32 %0, %1, %2" : "=v"(r.w) : "v"(hi.z), "v"(hi.w));
    return r;
}

// zero W1f+W2d and pre-fill out with b2 (k_gemm atomicAdds into out)
__global__ void k_zero(float4* __restrict__ ws4, float4* __restrict__ out4,
                       const float* __restrict__ b2) {
    int i = blockIdx.x * blockDim.x + threadIdx.x;
    if (i < ZERO_FLOAT4) {
        ws4[i] = make_float4(0.f, 0.f, 0.f, 0.f);
    } else {
        int j = i - ZERO_FLOAT4;
        if (j < OUT_FLOAT4) {
            int p = (j & 1) * 4;
            out4[j] = make_float4(b2[p], b2[p + 1], b2[p + 2], b2[p + 3]);
        }
    }
}

// scatter-add edges into dense W1f and W2d (handles duplicate edges by summing)
__global__ void k_build(const float* __restrict__ w1, const int* __restrict__ c1o,
                        const int* __restrict__ c1i,
                        const float* __restrict__ w2, const int* __restrict__ c2o,
                        const int* __restrict__ c2i,
                        float* __restrict__ W1f, float* __restrict__ W2d) {
    int i = blockIdx.x * blockDim.x + threadIdx.x;
    if (i < NNZ1) {
        atomicAdd(&W1f[(size_t)c1o[i] * NFEAT + c1i[i]], w1[i]);
    } else {
        int j = i - NNZ1;
        if (j < NNZ2) atomicAdd(&W2d[c2i[j] * NTGT + c2o[j]], w2[j]);
    }
}

// pack W1f into MFMA-fragment order (bf16). Unit u (16B = bf16x8):
//   lane=u&63, kslot=(u>>6)&1, i=(u>>7)&3, ks=(u>>9)&31, mt=u>>14
//   source row = mt*64 + i*16 + (lane&15), k = ks*64 + kslot*32 + (lane>>4)*8
// A wave's af[i][kslot] for (mt,ks) is then units [(mt*32+ks)*8 + i*2+kslot]*64
// + lane -- a fully coalesced 1KB read per fragment.
__global__ void k_pack(const float* __restrict__ W1f, unsigned short* __restrict__ W1p) {
    int u = blockIdx.x * blockDim.x + threadIdx.x;   // 262144 units
    int lane  = u & 63;
    int kslot = (u >> 6) & 1;
    int i     = (u >> 7) & 3;
    int ks    = (u >> 9) & 31;
    int mt    = u >> 14;
    int row = mt * 64 + i * 16 + (lane & 15);
    int k   = ks * 64 + kslot * 32 + (lane >> 4) * 8;
    const float* src = &W1f[(size_t)row * NFEAT + k];
    float4 lo = *(const float4*)src;
    float4 hi = *(const float4*)(src + 4);
    ((uint4*)W1p)[u] = pk8(lo, hi);
}

// bf16 MFMA GEMM, A direct-from-packed-global, reg-staged B (R12 loop),
// fused bias+sigmoid+layer2 epilogue (atomic into out).
__global__ __launch_bounds__(256) void k_gemm(const unsigned short* __restrict__ W1p,
                                              const float* __restrict__ x,
                                              const float* __restrict__ b1,
                                              const float* __restrict__ W2d,
                                              float* __restrict__ out) {
    __shared__ unsigned short ldsB[2][BN * BK];   // 2 x 8 KB (B only)
    __shared__ float s_w2[BM][NTGT];              // 4 KB
    __shared__ float s_b1[BM];                    // 512 B
    __shared__ float s_pt[2][BN][NTGT];           // 4 KB

    // XCD map: split M across XCD pairs (A = 4 m-tiles = 2 MB, L2-resident);
    // m fastest within XCD. Bijective: 8 xcd x 64 local = 8 m-tiles x 64 n-tiles.
    int bid = blockIdx.x;                  // 0..511
    int xcd = bid & 7;
    int loc = bid >> 3;                    // 0..63
    int m0  = ((xcd & 1) * 4 + (loc & 3)) * BM;
    int n0  = ((xcd >> 1) * 16 + (loc >> 2)) * BN;

    int tid  = threadIdx.x;
    int wv   = tid >> 6;
    int lane = tid & 63;
    int wm = wv >> 1, wn = wv & 1;         // wave grid 2m x 2n, wave tile 64x32
    int lr = lane & 15, lg = lane >> 4;

    // preload W2d + b1 slices for the epilogue (compiler orders via dataflow)
    for (int i = tid; i < BM * NTGT; i += 256)
        s_w2[i >> 3][i & 7] = W2d[(m0 + (i >> 3)) * NTGT + (i & 7)];
    if (tid < BM) s_b1[tid] = b1[m0 + tid];

    f32x4 zero4 = {0.f, 0.f, 0.f, 0.f};
    f32x4 acc[4][2];
#pragma unroll
    for (int i = 0; i < 4; ++i)
#pragma unroll
        for (int j = 0; j < 2; ++j) acc[i][j] = zero4;

    // ---- A: direct fragment loads from packed W1 ----
    // wave's 64-row m-group: mtA = m0/64 + wm; per step T, frag c = i*2+kslot:
    // unit = mtA*16384 + T*512 + c*64 + lane
    int mtA = (m0 >> 6) + wm;
    const bf16x8* gAf = (const bf16x8*)W1p + (size_t)mtA * 16384 + lane;

    // ---- B: reg-staged f32 -> bf16 -> XOR-swizzled LDS (R12 path) ----
    // B tile 64x64 = 512 16B-units; thread t handles units t, t+256.
    // unit u: row=u>>3, slot s=u&7; LDS unit = row*8 + (s ^ (row&7)).
    int r0 = tid >> 3, s0 = tid & 7;
    const float* gB0 = &x[(size_t)(n0 + r0) * NFEAT + s0 * 8];
    const float* gB1 = gB0 + 32 * NFEAT;
    const int iw0 = r0 * 8 + (s0 ^ (r0 & 7));
    const int iw1 = iw0 + 256;

    // two named register sets (rule #20: no runtime-indexed arrays)
    bf16x8 Af0[8], Af1[8];                 // A fragment regs (const-indexed)
    float4 B0a, B0b, B0c, B0d;
    float4 B1a, B1b, B1c, B1d;
    bf16x8 bg0[2], bg1[2];

#define LOADSA0(T) do {                                             \
        _Pragma("unroll")                                           \
        for (int c = 0; c < 8; ++c) Af0[c] = gAf[(T) * 512 + c * 64]; } while (0)
#define LOADSA1(T) do {                                             \
        _Pragma("unroll")                                           \
        for (int c = 0; c < 8; ++c) Af1[c] = gAf[(T) * 512 + c * 64]; } while (0)
#define LOADSB0(T) do { int kk = (T) * BK;                          \
        B0a = *(const float4*)(gB0 + kk); B0b = *(const float4*)(gB0 + kk + 4); \
        B0c = *(const float4*)(gB1 + kk); B0d = *(const float4*)(gB1 + kk + 4); } while (0)
#define LOADSB1(T) do { int kk = (T) * BK;                          \
        B1a = *(const float4*)(gB0 + kk); B1b = *(const float4*)(gB0 + kk + 4); \
        B1c = *(const float4*)(gB1 + kk); B1d = *(const float4*)(gB1 + kk + 4); } while (0)

#define STORE0(BUF) do {                                            \
        uint4* dB = (uint4*)&ldsB[BUF][0];                          \
        dB[iw0] = pk8(B0a, B0b); dB[iw1] = pk8(B0c, B0d); } while (0)
#define STORE1(BUF) do {                                            \
        uint4* dB = (uint4*)&ldsB[BUF][0];                          \
        dB[iw0] = pk8(B1a, B1b); dB[iw1] = pk8(B1c, B1d); } while (0)

#define READF(BUF) do {                                             \
        const unsigned short* bB = ldsB[BUF];                       \
        _Pragma("unroll")                                           \
        for (int j = 0; j < 2; ++j) {                               \
            int rowb = wn * 32 + j * 16 + lr;                       \
            bg0[j] = *(const bf16x8*)&bB[(rowb * 8 + ((lg)     ^ (rowb & 7))) * 8]; \
            bg1[j] = *(const bf16x8*)&bB[(rowb * 8 + ((4 + lg) ^ (rowb & 7))) * 8]; \
        }                                                           \
    } while (0)

#define MFMAS0() do {                                               \
        _Pragma("unroll")                                           \
        for (int i = 0; i < 4; ++i)                                 \
            _Pragma("unroll")                                       \
            for (int j = 0; j < 2; ++j)                             \
                acc[i][j] = __builtin_amdgcn_mfma_f32_16x16x32_bf16(Af0[i * 2],     bg0[j], acc[i][j], 0, 0, 0); \
        _Pragma("unroll")                                           \
        for (int i = 0; i < 4; ++i)                                 \
            _Pragma("unroll")                                       \
            for (int j = 0; j < 2; ++j)                             \
                acc[i][j] = __builtin_amdgcn_mfma_f32_16x16x32_bf16(Af0[i * 2 + 1], bg1[j], acc[i][j], 0, 0, 0); \
    } while (0)
#define MFMAS1() do {                                               \
        _Pragma("unroll")                                           \
        for (int i = 0; i < 4; ++i)                                 \
            _Pragma("unroll")                                       \
            for (int j = 0; j < 2; ++j)                             \
                acc[i][j] = __builtin_amdgcn_mfma_f32_16x16x32_bf16(Af1[i * 2],     bg0[j], acc[i][j], 0, 0, 0); \
        _Pragma("unroll")                                           \
        for (int i = 0; i < 4; ++i)                                 \
            _Pragma("unroll")                                       \
            for (int j = 0; j < 2; ++j)                             \
                acc[i][j] = __builtin_amdgcn_mfma_f32_16x16x32_bf16(Af1[i * 2 + 1], bg1[j], acc[i][j], 0, 0, 0); \
    } while (0)

#define LDSFENCE() asm volatile("s_waitcnt lgkmcnt(0)" ::: "memory")

    // prologue: tiles 0,1 -> regs (A direct, B staged); store B tile 0
    LOADSB0(0);
    LOADSA0(0);
    LOADSB1(1);
    LOADSA1(1);
    STORE0(0);            // compiler waits B set0's vmcnt precisely
    LDSFENCE();
    __builtin_amdgcn_s_barrier();

    // steady state: 15 pairs cover tiles 0..29.
    // A loads for t+2 issue AFTER MFMAS(t) (WAR on Af regs); they have two
    // barriers of slack before consumption at t+2.
#pragma unroll 1
    for (int p = 0; p < 15; ++p) {
        int e = 2 * p;
        // even: compute tile e; B(e+2) -> set0; B(e+1) -> buf1; A(e+2) -> Af0
        LOADSB0(e + 2);
        STORE1(1);        // waits B set1 only (set0 stays in flight)
        READF(0);
        MFMAS0();
        LOADSA0(e + 2);
        LDSFENCE();
        __builtin_amdgcn_s_barrier();
        // odd: compute tile e+1; B(e+3) -> set1; B(e+2) -> buf0; A(e+3) -> Af1
        LOADSB1(e + 3);
        STORE0(0);
        READF(1);
        MFMAS1();
        LOADSA1(e + 3);
        LDSFENCE();
        __builtin_amdgcn_s_barrier();
    }
    // tail: buf0 = B tile 30 ready; Af0 = 30; B set1/Af1 = tile 31 in flight
    STORE1(1);
    READF(0);
    MFMAS0();
    LDSFENCE();
    __builtin_amdgcn_s_barrier();
    READF(1);
    MFMAS1();

#undef LOADSA0
#undef LOADSA1
#undef LOADSB0
#undef LOADSB1
#undef STORE0
#undef STORE1
#undef READF
#undef MFMAS0
#undef MFMAS1
#undef LDSFENCE

    // ---- fused epilogue: h = sigmoid(acc + b1); pt[j][t] = sum_m h*W2d[m][t]
    // C/D layout: col(n) = lane&15, row(m) = (lane>>4)*4 + reg  [m89-verified]
    float pt[2][NTGT];
#pragma unroll
    for (int j = 0; j < 2; ++j)
#pragma unroll
        for (int t = 0; t < NTGT; ++t) pt[j][t] = 0.f;

#pragma unroll
    for (int i = 0; i < 4; ++i) {
#pragma unroll
        for (int r = 0; r < 4; ++r) {
            int ml = wm * 64 + i * 16 + lg * 4 + r;
            float bn = s_b1[ml];
#pragma unroll
            for (int j = 0; j < 2; ++j) {
                float h = 1.f / (1.f + __expf(-(acc[i][j][r] + bn)));
#pragma unroll
                for (int t = 0; t < NTGT; ++t)
                    pt[j][t] += h * s_w2[ml][t];
            }
        }
    }
    // reduce over lg (lanes lr+16*lg share the same n column)
#pragma unroll
    for (int j = 0; j < 2; ++j)
#pragma unroll
        for (int t = 0; t < NTGT; ++t) {
            float val = pt[j][t];
            val += __shfl_xor(val, 16, 64);
            val += __shfl_xor(val, 32, 64);
            pt[j][t] = val;
        }
    if (lg == 0) {
#pragma unroll
        for (int j = 0; j < 2; ++j) {
            int nl = wn * 32 + j * 16 + lr;
#pragma unroll
            for (int t = 0; t < NTGT; ++t)
                s_pt[wm][nl][t] = pt[j][t];
        }
    }
    __syncthreads();
    // atomic add 64 n x 8 t into out (pre-filled with b2); coalesced by tid
    for (int idx = tid; idx < BN * NTGT; idx += 256) {
        int nl = idx >> 3, t = idx & 7;
        atomicAdd(&out[(size_t)(n0 + nl) * NTGT + t], s_pt[0][nl][t] + s_pt[1][nl][t]);
    }
}

extern "C" void kernel_launch(void* const* d_in, const int* in_sizes, int n_in,
                              void* d_out, int out_size, void* d_ws, size_t ws_size,
                              hipStream_t stream) {
    (void)in_sizes; (void)n_in; (void)out_size; (void)ws_size;
    const float* x   = (const float*)d_in[0];
    const float* w1  = (const float*)d_in[1];
    const float* b1  = (const float*)d_in[2];
    const float* w2  = (const float*)d_in[3];
    const float* b2  = (const float*)d_in[4];
    const int*   c1o = (const int*)d_in[5];
    const int*   c1i = (const int*)d_in[6];
    const int*   c2o = (const int*)d_in[7];
    const int*   c2i = (const int*)d_in[8];
    float* out = (float*)d_out;

    char* ws = (char*)d_ws;
    float*          W1f  = (float*)(ws + OFF_W1F);
    float*          W2d  = (float*)(ws + OFF_W2D);
    unsigned short* W1p  = (unsigned short*)(ws + OFF_W1P);

    // zero W1f+W2d, pre-fill out with b2
    k_zero<<<(ZERO_FLOAT4 + OUT_FLOAT4 + 255) / 256, 256, 0, stream>>>(
        (float4*)ws, (float4*)out, b2);

    // dense weight build
    k_build<<<(NNZ1 + NNZ2) / 256, 256, 0, stream>>>(w1, c1o, c1i, w2, c2o, c2i, W1f, W2d);

    // pack W1 into MFMA-fragment order (bf16)
    k_pack<<<NNEUR * NFEAT / 8 / 256, 256, 0, stream>>>(W1f, W1p);

    // layer 1 GEMM + bias + sigmoid + layer-2 (atomic) all fused
    k_gemm<<<(NNEUR / BM) * (BATCH / BN), 256, 0, stream>>>(W1p, x, b1, W2d, out);
}